// Round 1
// baseline (1973.614 us; speedup 1.0000x reference)
//
#include <hip/hip_runtime.h>
#include <stdint.h>

#define Q    2048
#define NB   40000
#define NK   2048
#define ND   512
#define SCORE_SIZE (Q * NB)   // 81,920,000

typedef __bf16 bf16;
typedef bf16  bf16x8 __attribute__((ext_vector_type(8)));
typedef float f32x4  __attribute__((ext_vector_type(4)));

__device__ __forceinline__ unsigned short f2bf_rne(float f) {
    unsigned int u = __float_as_uint(f);
    u += 0x7FFFu + ((u >> 16) & 1u);
    return (unsigned short)(u >> 16);
}

// async global->LDS 16B: LDS side is wave-uniform base + lane*16 (m97/m104)
__device__ __forceinline__ void gl2lds16(const void* g, void* l) {
    __builtin_amdgcn_global_load_lds(
        (const __attribute__((address_space(1))) void*)g,
        (__attribute__((address_space(3))) void*)l, 16, 0, 0);
}

// ---------------------------------------------------------------- c2 = ||cb_k||^2
__global__ __launch_bounds__(256) void c2_kernel(const float* __restrict__ cb,
                                                 float* __restrict__ c2) {
    int wave = threadIdx.x >> 6, lane = threadIdx.x & 63;
    int row  = blockIdx.x * 4 + wave;          // grid = NK/4 = 512
    const float4* p = (const float4*)(cb + (size_t)row * ND);
    float4 a = p[lane];
    float4 b = p[lane + 64];
    float s = a.x*a.x + a.y*a.y + a.z*a.z + a.w*a.w
            + b.x*b.x + b.y*b.y + b.z*b.z + b.w*b.w;
    #pragma unroll
    for (int off = 32; off; off >>= 1) s += __shfl_down(s, off);
    if (lane == 0) c2[row] = s;
}

// ---------------------------------------------------------- fp32 -> bf16 (RNE)
__global__ __launch_bounds__(256) void cvt_bf16_kernel(const float* __restrict__ src,
                                                       unsigned short* __restrict__ dst) {
    int i = (blockIdx.x * 256 + threadIdx.x) * 4;
    float4 v = *(const float4*)(src + i);
    uint2 u;
    u.x = (unsigned int)f2bf_rne(v.x) | ((unsigned int)f2bf_rne(v.y) << 16);
    u.y = (unsigned int)f2bf_rne(v.z) | ((unsigned int)f2bf_rne(v.w) << 16);
    *(uint2*)(dst + i) = u;
}

// top-2 insert with first-index tie-break
__device__ __forceinline__ void top2_insert(float& v1, int& i1, float& v2, int& i2,
                                            float w, int j) {
    if (w < v1 || (w == v1 && j < i1)) { v2 = v1; i2 = i1; v1 = w; i1 = j; }
    else if (w < v2 || (w == v2 && j < i2)) { v2 = w; i2 = j; }
}

// shared MFMA inner tile: 2 kq x (8 ds_read_b128 + 16 MFMA), XOR chunk swizzle
__device__ __forceinline__ void mfma_tile(const unsigned short* __restrict__ Ab,
                                          const unsigned short* __restrict__ Bb,
                                          f32x4 (&acc)[4][4],
                                          int wm, int wn, int lr, int quad) {
    #pragma unroll
    for (int kq = 0; kq < 2; ++kq) {
        bf16x8 af[4], bfr[4];
        #pragma unroll
        for (int mi = 0; mi < 4; ++mi) {
            int r = wm * 64 + mi * 16 + lr;
            int ch = (kq * 4 + quad) ^ (lr & 7);
            af[mi] = *(const bf16x8*)(Ab + ((size_t)r * 8 + ch) * 8);
        }
        #pragma unroll
        for (int ni = 0; ni < 4; ++ni) {
            int r = wn * 64 + ni * 16 + lr;
            int ch = (kq * 4 + quad) ^ (lr & 7);
            bfr[ni] = *(const bf16x8*)(Bb + ((size_t)r * 8 + ch) * 8);
        }
        #pragma unroll
        for (int mi = 0; mi < 4; ++mi)
            #pragma unroll
            for (int ni = 0; ni < 4; ++ni)
                acc[mi][ni] = __builtin_amdgcn_mfma_f32_16x16x32_bf16(
                    af[mi], bfr[ni], acc[mi][ni], 0, 0, 0);
    }
}

// bijective chunked XCD swizzle (m204); nwg = 5008 = 8 * 626, divisible by 8.
// Fast axis = 16 k/m-tiles so the 16 blocks sharing a 128-row panel run adjacent.
__device__ __forceinline__ void tile_coords(int bid, int& fast16, int& slow313) {
    int wg = (bid & 7) * 626 + (bid >> 3);
    fast16  = wg & 15;
    slow313 = wg >> 4;
}

// ---------------- approx distance GEMM: s(b,k) = c2[k] - 2*bf16dot(x_b, c_k)
// 128x128 tile, BK=64, double-buffered LDS (T3 2-phase): stage(t+1) issued
// BEFORE compute(t); single __syncthreads per K-step drains vmcnt after compute.
template<bool PRE>
__device__ __forceinline__ void stage_dist(
        const float* __restrict__ entf, const unsigned short* __restrict__ ehi,
        const unsigned short* __restrict__ chi,
        unsigned short* Eb, unsigned short* Cb,
        int b0, int k0, int kt, int tid, int wave) {
    #pragma unroll
    for (int j = 0; j < 4; ++j) {
        int q = j * 256 + tid;            // linear LDS chunk id (lane-linear)
        int r = q >> 3;
        int cs = (q & 7) ^ (r & 7);       // pre-swizzled global chunk
        gl2lds16(chi + (size_t)(k0 + r) * ND + kt + cs * 8,
                 Cb + (size_t)(j * 256 + wave * 64) * 8);   // wave-uniform base
        int br = b0 + r; br = br < NB ? br : NB - 1;
        if (PRE) {
            gl2lds16(ehi + (size_t)br * ND + kt + cs * 8,
                     Eb + (size_t)(j * 256 + wave * 64) * 8);
        } else {
            const float* s = entf + (size_t)br * ND + kt + cs * 8;
            float4 a = *(const float4*)s;
            float4 b = *(const float4*)(s + 4);
            uint4 hp;
            hp.x = (unsigned int)f2bf_rne(a.x) | ((unsigned int)f2bf_rne(a.y) << 16);
            hp.y = (unsigned int)f2bf_rne(a.z) | ((unsigned int)f2bf_rne(a.w) << 16);
            hp.z = (unsigned int)f2bf_rne(b.x) | ((unsigned int)f2bf_rne(b.y) << 16);
            hp.w = (unsigned int)f2bf_rne(b.z) | ((unsigned int)f2bf_rne(b.w) << 16);
            *(uint4*)(Eb + (size_t)q * 8) = hp;
        }
    }
}

template<bool PRE>
__global__ __launch_bounds__(256) void dist_mfma_kernel(
        const float* __restrict__ entf, const unsigned short* __restrict__ ehi,
        const unsigned short* __restrict__ chi,
        const float* __restrict__ c2g, float4* __restrict__ partial) {
    __shared__ unsigned short Es[2][128 * 64];   // 2 x 16 KB
    __shared__ unsigned short Cs[2][128 * 64];   // 2 x 16 KB  (64 KB total)
    int tid = threadIdx.x;
    int by, bx;
    tile_coords(blockIdx.x, by, bx);   // by: 16 k-tiles (fast), bx: 313 b-tiles
    int b0 = bx * 128;
    int k0 = by * 128;
    int lane = tid & 63, wave = tid >> 6;
    int wm = wave >> 1, wn = wave & 1;
    int lr = lane & 15, quad = lane >> 4;

    f32x4 acc[4][4] = {};

    // prologue: stage tile 0, full drain once
    stage_dist<PRE>(entf, ehi, chi, Es[0], Cs[0], b0, k0, 0, tid, wave);
    __syncthreads();

    #pragma unroll
    for (int t = 0; t < 8; ++t) {                 // ND/64 = 8 K-steps
        if (t < 7)
            stage_dist<PRE>(entf, ehi, chi, Es[(t + 1) & 1], Cs[(t + 1) & 1],
                            b0, k0, (t + 1) * 64, tid, wave);
        mfma_tile(Es[t & 1], Cs[t & 1], acc, wm, wn, lr, quad);
        __syncthreads();  // drains vmcnt(0): prefetched tile t+1 is ready
    }

    float c2v[4];
    #pragma unroll
    for (int ni = 0; ni < 4; ++ni) c2v[ni] = c2g[k0 + wn * 64 + ni * 16 + lr];

    #pragma unroll
    for (int mi = 0; mi < 4; ++mi) {
        #pragma unroll
        for (int rr = 0; rr < 4; ++rr) {
            float v1 = 3.4e38f, v2 = 3.4e38f;
            int i1 = 0x7FFFFFFF, i2 = 0x7FFFFFFF;
            #pragma unroll
            for (int ni = 0; ni < 4; ++ni) {
                float w = c2v[ni] - 2.0f * acc[mi][ni][rr];
                top2_insert(v1, i1, v2, i2, w, k0 + wn * 64 + ni * 16 + lr);
            }
            #pragma unroll
            for (int off = 1; off < 16; off <<= 1) {
                float ov1 = __shfl_xor(v1, off); int oi1 = __shfl_xor(i1, off);
                float ov2 = __shfl_xor(v2, off); int oi2 = __shfl_xor(i2, off);
                top2_insert(v1, i1, v2, i2, ov1, oi1);
                top2_insert(v1, i1, v2, i2, ov2, oi2);
            }
            int b = b0 + wm * 64 + mi * 16 + quad * 4 + rr;
            if (lr == 0 && b < NB)
                partial[(size_t)(by * 2 + wn) * NB + b] =
                    make_float4(v1, __int_as_float(i1), v2, __int_as_float(i2));
        }
    }
}

// ------------------------------ merge 32 group top-2s -> global approx top-8
__global__ __launch_bounds__(256) void cand_merge_kernel(
        const float4* __restrict__ partial, int* __restrict__ cand) {
    int b = blockIdx.x * 256 + threadIdx.x;
    if (b >= NB) return;
    float tv[8]; int ti[8];
    #pragma unroll
    for (int s = 0; s < 8; ++s) { tv[s] = 3.4e38f; ti[s] = 0x7FFFFFFF; }
    for (int g = 0; g < 32; ++g) {
        float4 p = partial[(size_t)g * NB + b];
        float pv[2] = {p.x, p.z};
        int   pi[2] = {__float_as_int(p.y), __float_as_int(p.w)};
        #pragma unroll
        for (int t = 0; t < 2; ++t) {
            float w = pv[t]; int j = pi[t];
            #pragma unroll
            for (int s = 0; s < 8; ++s) {
                if (w < tv[s] || (w == tv[s] && j < ti[s])) {
                    float tmpv = tv[s]; int tmpi = ti[s];
                    tv[s] = w; ti[s] = j; w = tmpv; j = tmpi;
                }
            }
        }
    }
    #pragma unroll
    for (int s = 0; s < 8; ++s) cand[(size_t)b * 8 + s] = ti[s];
}

// ------- exact fp32 rescore of 8 candidates + fused quant gather + vq_loss
__global__ __launch_bounds__(512) void rescore_kernel(
        const float* __restrict__ ent, const float* __restrict__ cb,
        const float* __restrict__ c2g, const int* __restrict__ cand,
        unsigned short* __restrict__ quantb, float* __restrict__ out_idx,
        float* __restrict__ acc) {
    int b = blockIdx.x;                 // grid = NB, 8 waves = 8 candidates
    int wave = threadIdx.x >> 6, lane = threadIdx.x & 63;
    int k = cand[(size_t)b * 8 + wave];
    const float4* xp = (const float4*)(ent + (size_t)b * ND);
    const float4* cp = (const float4*)(cb + (size_t)k * ND);
    float4 x0 = xp[lane * 2], x1 = xp[lane * 2 + 1];
    float4 c0 = cp[lane * 2], c1 = cp[lane * 2 + 1];
    float s = x0.x*c0.x + x0.y*c0.y + x0.z*c0.z + x0.w*c0.w
            + x1.x*c1.x + x1.y*c1.y + x1.z*c1.z + x1.w*c1.w;
    #pragma unroll
    for (int off = 32; off; off >>= 1) s += __shfl_down(s, off);
    __shared__ float vws[8];
    __shared__ int   kws[8];
    __shared__ int   win;
    if (lane == 0) { vws[wave] = c2g[k] - 2.0f * s; kws[wave] = k; }
    __syncthreads();
    if (threadIdx.x == 0) {
        float bv = vws[0]; int bk = kws[0], bw = 0;
        #pragma unroll
        for (int w = 1; w < 8; ++w) {
            if (vws[w] < bv || (vws[w] == bv && kws[w] < bk)) {
                bv = vws[w]; bk = kws[w]; bw = w;
            }
        }
        win = bw;
        out_idx[b] = (float)bk;
    }
    __syncthreads();
    if (wave == win) {
        uint4 qp;
        qp.x = (unsigned int)f2bf_rne(c0.x) | ((unsigned int)f2bf_rne(c0.y) << 16);
        qp.y = (unsigned int)f2bf_rne(c0.z) | ((unsigned int)f2bf_rne(c0.w) << 16);
        qp.z = (unsigned int)f2bf_rne(c1.x) | ((unsigned int)f2bf_rne(c1.y) << 16);
        qp.w = (unsigned int)f2bf_rne(c1.z) | ((unsigned int)f2bf_rne(c1.w) << 16);
        *(uint4*)(quantb + (size_t)b * ND + lane * 8) = qp;
        float d0 = c0.x - x0.x, d1 = c0.y - x0.y, d2 = c0.z - x0.z, d3 = c0.w - x0.w;
        float d4 = c1.x - x1.x, d5 = c1.y - x1.y, d6 = c1.z - x1.z, d7 = c1.w - x1.w;
        float l = d0*d0 + d1*d1 + d2*d2 + d3*d3 + d4*d4 + d5*d5 + d6*d6 + d7*d7;
        #pragma unroll
        for (int off = 32; off; off >>= 1) l += __shfl_down(l, off);
        if (lane == 0) atomicAdd(acc, l);
    }
}

__global__ void vq_final_kernel(const float* __restrict__ acc, float* __restrict__ out) {
    out[0] = 1.25f * acc[0] / (float)(NB * ND);
}

// ---------- score = query @ quant^T, double-buffered 2-phase pipeline
__device__ __forceinline__ void stage_score(
        const unsigned short* __restrict__ Aq, const unsigned short* __restrict__ Bq,
        unsigned short* Ab, unsigned short* Bb,
        int m0, int n0, int kt, int tid, int wave) {
    #pragma unroll
    for (int j = 0; j < 4; ++j) {
        int q = j * 256 + tid;
        int r = q >> 3;
        int cs = (q & 7) ^ (r & 7);
        gl2lds16(Aq + (size_t)(m0 + r) * ND + kt + cs * 8,
                 Ab + (size_t)(j * 256 + wave * 64) * 8);
        int nr = n0 + r; nr = nr < NB ? nr : NB - 1;
        gl2lds16(Bq + (size_t)nr * ND + kt + cs * 8,
                 Bb + (size_t)(j * 256 + wave * 64) * 8);
    }
}

__global__ __launch_bounds__(256) void score_kernel(
        const unsigned short* __restrict__ Aq, const unsigned short* __restrict__ Bq,
        float* __restrict__ C) {
    __shared__ unsigned short As[2][128 * 64];
    __shared__ unsigned short Bs[2][128 * 64];
    int tid = threadIdx.x;
    int bm, bn;
    tile_coords(blockIdx.x, bm, bn);   // bm: 16 Q-tiles (fast), bn: 313 B-tiles
    int m0 = bm * 128;
    int n0 = bn * 128;
    int lane = tid & 63, wave = tid >> 6;
    int wm = wave >> 1, wn = wave & 1;
    int lr = lane & 15, quad = lane >> 4;

    f32x4 acc[4][4] = {};

    stage_score(Aq, Bq, As[0], Bs[0], m0, n0, 0, tid, wave);
    __syncthreads();

    #pragma unroll
    for (int t = 0; t < 8; ++t) {
        if (t < 7)
            stage_score(Aq, Bq, As[(t + 1) & 1], Bs[(t + 1) & 1],
                        m0, n0, (t + 1) * 64, tid, wave);
        mfma_tile(As[t & 1], Bs[t & 1], acc, wm, wn, lr, quad);
        __syncthreads();
    }

    // C/D layout (verified m89/m91): col = lane&15, row = (lane>>4)*4 + reg
    #pragma unroll
    for (int mi = 0; mi < 4; ++mi) {
        #pragma unroll
        for (int ni = 0; ni < 4; ++ni) {
            int col = n0 + wn * 64 + ni * 16 + lr;
            if (col < NB) {
                #pragma unroll
                for (int r = 0; r < 4; ++r) {
                    int row = m0 + wm * 64 + mi * 16 + quad * 4 + r;
                    C[(size_t)row * NB + col] = acc[mi][ni][r];
                }
            }
        }
    }
}

extern "C" void kernel_launch(void* const* d_in, const int* in_sizes, int n_in,
                              void* d_out, int out_size, void* d_ws, size_t ws_size,
                              hipStream_t stream) {
    const float* qry = (const float*)d_in[0];   // (2048, 512)
    const float* ent = (const float*)d_in[1];   // (40000, 512)
    const float* cb  = (const float*)d_in[2];   // (2048, 512)
    float* out = (float*)d_out;                 // [score | vq_loss | idx]

    char* ws = (char*)d_ws;
    const bool pre = ws_size >= 100ull * 1024 * 1024;

    // region0: partial (20.48 MB) during dist/merge, then quantb (40.96 MB).
    // rescore (writer of quantb) runs after cand_merge (last reader of partial).
    float4*         partial = (float4*)(ws);
    unsigned short* quantb  = (unsigned short*)(ws);
    size_t off = 40960000;
    unsigned short* ehi = nullptr;
    if (pre) { ehi = (unsigned short*)(ws + off); off += 40960000; }
    unsigned short* chi = (unsigned short*)(ws + off); off += 2097152;
    unsigned short* qb  = (unsigned short*)(ws + off); off += 2097152;
    int*            cand= (int*)(ws + off);            off += 1280000;
    float*          c2  = (float*)(ws + off);          off += 8192;
    float*          acc = (float*)(ws + off);          off += 4;

    hipMemsetAsync(acc, 0, sizeof(float), stream);

    c2_kernel<<<NK / 4, 256, 0, stream>>>(cb, c2);
    cvt_bf16_kernel<<<NK * ND / 1024, 256, 0, stream>>>(cb, chi);
    cvt_bf16_kernel<<<Q * ND / 1024, 256, 0, stream>>>(qry, qb);
    if (pre) {
        cvt_bf16_kernel<<<NB * ND / 1024, 256, 0, stream>>>(ent, ehi);
        dist_mfma_kernel<true><<<5008, 256, 0, stream>>>(
            ent, ehi, chi, c2, partial);
    } else {
        dist_mfma_kernel<false><<<5008, 256, 0, stream>>>(
            ent, nullptr, chi, c2, partial);
    }
    cand_merge_kernel<<<(NB + 255) / 256, 256, 0, stream>>>(partial, cand);
    rescore_kernel<<<NB, 512, 0, stream>>>(ent, cb, c2, cand, quantb,
                                           out + SCORE_SIZE + 1, acc);
    vq_final_kernel<<<1, 1, 0, stream>>>(acc, out + SCORE_SIZE);
    score_kernel<<<5008, 256, 0, stream>>>(qb, quantb, out);
}

// Round 2
// 1936.896 us; speedup vs baseline: 1.0190x; 1.0190x over previous
//
#include <hip/hip_runtime.h>
#include <stdint.h>

#define Q    2048
#define NB   40000
#define NK   2048
#define ND   512
#define SCORE_SIZE (Q * NB)   // 81,920,000

#define BM 256
#define BN 256
#define BK 64

typedef __bf16 bf16;
typedef bf16  bf16x8 __attribute__((ext_vector_type(8)));
typedef float f32x4  __attribute__((ext_vector_type(4)));

__device__ __forceinline__ unsigned short f2bf_rne(float f) {
    unsigned int u = __float_as_uint(f);
    u += 0x7FFFu + ((u >> 16) & 1u);
    return (unsigned short)(u >> 16);
}

// async global->LDS 16B: LDS side is wave-uniform base + lane*16 (m97/m104)
__device__ __forceinline__ void gl2lds16(const void* g, void* l) {
    __builtin_amdgcn_global_load_lds(
        (const __attribute__((address_space(1))) void*)g,
        (__attribute__((address_space(3))) void*)l, 16, 0, 0);
}

// ---------------------------------------------------------------- c2 = ||cb_k||^2
__global__ __launch_bounds__(256) void c2_kernel(const float* __restrict__ cb,
                                                 float* __restrict__ c2) {
    int wave = threadIdx.x >> 6, lane = threadIdx.x & 63;
    int row  = blockIdx.x * 4 + wave;          // grid = NK/4 = 512
    const float4* p = (const float4*)(cb + (size_t)row * ND);
    float4 a = p[lane];
    float4 b = p[lane + 64];
    float s = a.x*a.x + a.y*a.y + a.z*a.z + a.w*a.w
            + b.x*b.x + b.y*b.y + b.z*b.z + b.w*b.w;
    #pragma unroll
    for (int off = 32; off; off >>= 1) s += __shfl_down(s, off);
    if (lane == 0) c2[row] = s;
}

// ---------------------------------------------------------- fp32 -> bf16 (RNE)
__global__ __launch_bounds__(256) void cvt_bf16_kernel(const float* __restrict__ src,
                                                       unsigned short* __restrict__ dst) {
    int i = (blockIdx.x * 256 + threadIdx.x) * 4;
    float4 v = *(const float4*)(src + i);
    uint2 u;
    u.x = (unsigned int)f2bf_rne(v.x) | ((unsigned int)f2bf_rne(v.y) << 16);
    u.y = (unsigned int)f2bf_rne(v.z) | ((unsigned int)f2bf_rne(v.w) << 16);
    *(uint2*)(dst + i) = u;
}

// top-2 insert with first-index tie-break
__device__ __forceinline__ void top2_insert(float& v1, int& i1, float& v2, int& i2,
                                            float w, int j) {
    if (w < v1 || (w == v1 && j < i1)) { v2 = v1; i2 = i1; v1 = w; i1 = j; }
    else if (w < v2 || (w == v2 && j < i2)) { v2 = w; i2 = j; }
}

// 256x256 tile MFMA step: 8 waves (2M x 4N), per-wave 128x64 output.
// Fragment/swizzle formulas identical to the verified 128-tile version
// (r&7 == lr&7 still holds since all row bases are multiples of 16).
__device__ __forceinline__ void mfma_tile256(const unsigned short* __restrict__ Ab,
                                             const unsigned short* __restrict__ Bb,
                                             f32x4 (&acc)[8][4],
                                             int wm, int wn, int lr, int quad) {
    #pragma unroll
    for (int kq = 0; kq < 2; ++kq) {
        bf16x8 af[8], bfr[4];
        #pragma unroll
        for (int mi = 0; mi < 8; ++mi) {
            int r = wm * 128 + mi * 16 + lr;
            int ch = (kq * 4 + quad) ^ (lr & 7);
            af[mi] = *(const bf16x8*)(Ab + ((size_t)r * 8 + ch) * 8);
        }
        #pragma unroll
        for (int ni = 0; ni < 4; ++ni) {
            int r = wn * 64 + ni * 16 + lr;
            int ch = (kq * 4 + quad) ^ (lr & 7);
            bfr[ni] = *(const bf16x8*)(Bb + ((size_t)r * 8 + ch) * 8);
        }
        #pragma unroll
        for (int mi = 0; mi < 8; ++mi)
            #pragma unroll
            for (int ni = 0; ni < 4; ++ni)
                acc[mi][ni] = __builtin_amdgcn_mfma_f32_16x16x32_bf16(
                    af[mi], bfr[ni], acc[mi][ni], 0, 0, 0);
    }
}

// bijective chunked XCD swizzle: nwg = 1256 = 8 * 157.
// fast8 = the 8-tile axis so blocks sharing a 256-row panel run on one XCD.
__device__ __forceinline__ void tile_coords8(int bid, int& fast8, int& slow157) {
    int wg = (bid & 7) * 157 + (bid >> 3);
    fast8   = wg & 7;
    slow157 = wg >> 3;
}

// ---------------- approx distance GEMM: s(b,k) = c2[k] - 2*bf16dot(x_b, c_k)
template<bool PRE>
__device__ __forceinline__ void stage_dist256(
        const float* __restrict__ entf, const unsigned short* __restrict__ ehi,
        const unsigned short* __restrict__ chi,
        unsigned short* Eb, unsigned short* Cb,
        int b0, int k0, int kt, int tid, int wave) {
    #pragma unroll
    for (int j = 0; j < 4; ++j) {
        int q = j * 512 + tid;            // chunk id within 256x64 tile
        int r = q >> 3;                   // 0..255
        int cs = (q & 7) ^ (r & 7);       // pre-swizzled global chunk
        gl2lds16(chi + (size_t)(k0 + r) * ND + kt + cs * 8,
                 Cb + (size_t)(j * 512 + wave * 64) * 8);   // wave-uniform base
        int br = b0 + r; br = br < NB ? br : NB - 1;
        if (PRE) {
            gl2lds16(ehi + (size_t)br * ND + kt + cs * 8,
                     Eb + (size_t)(j * 512 + wave * 64) * 8);
        } else {
            const float* s = entf + (size_t)br * ND + kt + cs * 8;
            float4 a = *(const float4*)s;
            float4 b = *(const float4*)(s + 4);
            uint4 hp;
            hp.x = (unsigned int)f2bf_rne(a.x) | ((unsigned int)f2bf_rne(a.y) << 16);
            hp.y = (unsigned int)f2bf_rne(a.z) | ((unsigned int)f2bf_rne(a.w) << 16);
            hp.z = (unsigned int)f2bf_rne(b.x) | ((unsigned int)f2bf_rne(b.y) << 16);
            hp.w = (unsigned int)f2bf_rne(b.z) | ((unsigned int)f2bf_rne(b.w) << 16);
            *(uint4*)(Eb + (size_t)q * 8) = hp;
        }
    }
}

template<bool PRE>
__global__ __launch_bounds__(512, 2) void dist_mfma_kernel(
        const float* __restrict__ entf, const unsigned short* __restrict__ ehi,
        const unsigned short* __restrict__ chi,
        const float* __restrict__ c2g, float4* __restrict__ partial) {
    __shared__ unsigned short Es[2][BM * BK];   // 2 x 32 KB
    __shared__ unsigned short Cs[2][BN * BK];   // 2 x 32 KB  (128 KB total)
    int tid = threadIdx.x;
    int by, bx;
    tile_coords8(blockIdx.x, by, bx);  // by: 8 k-tiles (fast), bx: 157 b-tiles
    int b0 = bx * BM;
    int k0 = by * BN;
    int lane = tid & 63, wave = tid >> 6;
    int wm = wave >> 2, wn = wave & 3;
    int lr = lane & 15, quad = lane >> 4;

    f32x4 acc[8][4] = {};

    stage_dist256<PRE>(entf, ehi, chi, Es[0], Cs[0], b0, k0, 0, tid, wave);
    __syncthreads();

    for (int t = 0; t < 8; ++t) {                 // ND/64 = 8 K-steps
        if (t < 7)
            stage_dist256<PRE>(entf, ehi, chi, Es[(t + 1) & 1], Cs[(t + 1) & 1],
                               b0, k0, (t + 1) * BK, tid, wave);
        mfma_tile256(Es[t & 1], Cs[t & 1], acc, wm, wn, lr, quad);
        __syncthreads();  // drains vmcnt(0): prefetched tile t+1 is ready
    }

    float c2v[4];
    #pragma unroll
    for (int ni = 0; ni < 4; ++ni) c2v[ni] = c2g[k0 + wn * 64 + ni * 16 + lr];

    // top-2 per 64-code group; group id = by*4 + wn in [0,32) -> cand_merge unchanged
    #pragma unroll
    for (int mi = 0; mi < 8; ++mi) {
        #pragma unroll
        for (int rr = 0; rr < 4; ++rr) {
            float v1 = 3.4e38f, v2 = 3.4e38f;
            int i1 = 0x7FFFFFFF, i2 = 0x7FFFFFFF;
            #pragma unroll
            for (int ni = 0; ni < 4; ++ni) {
                float w = c2v[ni] - 2.0f * acc[mi][ni][rr];
                top2_insert(v1, i1, v2, i2, w, k0 + wn * 64 + ni * 16 + lr);
            }
            #pragma unroll
            for (int off = 1; off < 16; off <<= 1) {
                float ov1 = __shfl_xor(v1, off); int oi1 = __shfl_xor(i1, off);
                float ov2 = __shfl_xor(v2, off); int oi2 = __shfl_xor(i2, off);
                top2_insert(v1, i1, v2, i2, ov1, oi1);
                top2_insert(v1, i1, v2, i2, ov2, oi2);
            }
            int b = b0 + wm * 128 + mi * 16 + quad * 4 + rr;
            if (lr == 0 && b < NB)
                partial[(size_t)(by * 4 + wn) * NB + b] =
                    make_float4(v1, __int_as_float(i1), v2, __int_as_float(i2));
        }
    }
}

// ------------------------------ merge 32 group top-2s -> global approx top-8
__global__ __launch_bounds__(256) void cand_merge_kernel(
        const float4* __restrict__ partial, int* __restrict__ cand) {
    int b = blockIdx.x * 256 + threadIdx.x;
    if (b >= NB) return;
    float tv[8]; int ti[8];
    #pragma unroll
    for (int s = 0; s < 8; ++s) { tv[s] = 3.4e38f; ti[s] = 0x7FFFFFFF; }
    for (int g = 0; g < 32; ++g) {
        float4 p = partial[(size_t)g * NB + b];
        float pv[2] = {p.x, p.z};
        int   pi[2] = {__float_as_int(p.y), __float_as_int(p.w)};
        #pragma unroll
        for (int t = 0; t < 2; ++t) {
            float w = pv[t]; int j = pi[t];
            #pragma unroll
            for (int s = 0; s < 8; ++s) {
                if (w < tv[s] || (w == tv[s] && j < ti[s])) {
                    float tmpv = tv[s]; int tmpi = ti[s];
                    tv[s] = w; ti[s] = j; w = tmpv; j = tmpi;
                }
            }
        }
    }
    #pragma unroll
    for (int s = 0; s < 8; ++s) cand[(size_t)b * 8 + s] = ti[s];
}

// ------- exact fp32 rescore of 8 candidates + fused quant gather + vq_loss
__global__ __launch_bounds__(512) void rescore_kernel(
        const float* __restrict__ ent, const float* __restrict__ cb,
        const float* __restrict__ c2g, const int* __restrict__ cand,
        unsigned short* __restrict__ quantb, float* __restrict__ out_idx,
        float* __restrict__ acc) {
    int b = blockIdx.x;                 // grid = NB, 8 waves = 8 candidates
    int wave = threadIdx.x >> 6, lane = threadIdx.x & 63;
    int k = cand[(size_t)b * 8 + wave];
    const float4* xp = (const float4*)(ent + (size_t)b * ND);
    const float4* cp = (const float4*)(cb + (size_t)k * ND);
    float4 x0 = xp[lane * 2], x1 = xp[lane * 2 + 1];
    float4 c0 = cp[lane * 2], c1 = cp[lane * 2 + 1];
    float s = x0.x*c0.x + x0.y*c0.y + x0.z*c0.z + x0.w*c0.w
            + x1.x*c1.x + x1.y*c1.y + x1.z*c1.z + x1.w*c1.w;
    #pragma unroll
    for (int off = 32; off; off >>= 1) s += __shfl_down(s, off);
    __shared__ float vws[8];
    __shared__ int   kws[8];
    __shared__ int   win;
    if (lane == 0) { vws[wave] = c2g[k] - 2.0f * s; kws[wave] = k; }
    __syncthreads();
    if (threadIdx.x == 0) {
        float bv = vws[0]; int bk = kws[0], bw = 0;
        #pragma unroll
        for (int w = 1; w < 8; ++w) {
            if (vws[w] < bv || (vws[w] == bv && kws[w] < bk)) {
                bv = vws[w]; bk = kws[w]; bw = w;
            }
        }
        win = bw;
        out_idx[b] = (float)bk;
    }
    __syncthreads();
    if (wave == win) {
        uint4 qp;
        qp.x = (unsigned int)f2bf_rne(c0.x) | ((unsigned int)f2bf_rne(c0.y) << 16);
        qp.y = (unsigned int)f2bf_rne(c0.z) | ((unsigned int)f2bf_rne(c0.w) << 16);
        qp.z = (unsigned int)f2bf_rne(c1.x) | ((unsigned int)f2bf_rne(c1.y) << 16);
        qp.w = (unsigned int)f2bf_rne(c1.z) | ((unsigned int)f2bf_rne(c1.w) << 16);
        *(uint4*)(quantb + (size_t)b * ND + lane * 8) = qp;
        float d0 = c0.x - x0.x, d1 = c0.y - x0.y, d2 = c0.z - x0.z, d3 = c0.w - x0.w;
        float d4 = c1.x - x1.x, d5 = c1.y - x1.y, d6 = c1.z - x1.z, d7 = c1.w - x1.w;
        float l = d0*d0 + d1*d1 + d2*d2 + d3*d3 + d4*d4 + d5*d5 + d6*d6 + d7*d7;
        #pragma unroll
        for (int off = 32; off; off >>= 1) l += __shfl_down(l, off);
        if (lane == 0) atomicAdd(acc, l);
    }
}

__global__ void vq_final_kernel(const float* __restrict__ acc, float* __restrict__ out) {
    out[0] = 1.25f * acc[0] / (float)(NB * ND);
}

// ---------- score = query @ quant^T, same 256x256 2-phase structure
__device__ __forceinline__ void stage_score256(
        const unsigned short* __restrict__ Aq, const unsigned short* __restrict__ Bq,
        unsigned short* Ab, unsigned short* Bb,
        int m0, int n0, int kt, int tid, int wave) {
    #pragma unroll
    for (int j = 0; j < 4; ++j) {
        int q = j * 512 + tid;
        int r = q >> 3;
        int cs = (q & 7) ^ (r & 7);
        gl2lds16(Aq + (size_t)(m0 + r) * ND + kt + cs * 8,
                 Ab + (size_t)(j * 512 + wave * 64) * 8);
        int nr = n0 + r; nr = nr < NB ? nr : NB - 1;
        gl2lds16(Bq + (size_t)nr * ND + kt + cs * 8,
                 Bb + (size_t)(j * 512 + wave * 64) * 8);
    }
}

__global__ __launch_bounds__(512, 2) void score_kernel(
        const unsigned short* __restrict__ Aq, const unsigned short* __restrict__ Bq,
        float* __restrict__ C) {
    __shared__ unsigned short As[2][BM * BK];
    __shared__ unsigned short Bs[2][BN * BK];
    int tid = threadIdx.x;
    int bm, bn;
    tile_coords8(blockIdx.x, bm, bn);  // bm: 8 Q-tiles (fast), bn: 157 B-tiles
    int m0 = bm * BM;
    int n0 = bn * BN;
    int lane = tid & 63, wave = tid >> 6;
    int wm = wave >> 2, wn = wave & 3;
    int lr = lane & 15, quad = lane >> 4;

    f32x4 acc[8][4] = {};

    stage_score256(Aq, Bq, As[0], Bs[0], m0, n0, 0, tid, wave);
    __syncthreads();

    for (int t = 0; t < 8; ++t) {
        if (t < 7)
            stage_score256(Aq, Bq, As[(t + 1) & 1], Bs[(t + 1) & 1],
                           m0, n0, (t + 1) * BK, tid, wave);
        mfma_tile256(As[t & 1], Bs[t & 1], acc, wm, wn, lr, quad);
        __syncthreads();
    }

    // C/D layout (verified m89/m91): col = lane&15, row = (lane>>4)*4 + reg
    #pragma unroll
    for (int mi = 0; mi < 8; ++mi) {
        #pragma unroll
        for (int ni = 0; ni < 4; ++ni) {
            int col = n0 + wn * 64 + ni * 16 + lr;
            if (col < NB) {
                #pragma unroll
                for (int r = 0; r < 4; ++r) {
                    int row = m0 + wm * 128 + mi * 16 + quad * 4 + r;
                    C[(size_t)row * NB + col] = acc[mi][ni][r];
                }
            }
        }
    }
}

extern "C" void kernel_launch(void* const* d_in, const int* in_sizes, int n_in,
                              void* d_out, int out_size, void* d_ws, size_t ws_size,
                              hipStream_t stream) {
    const float* qry = (const float*)d_in[0];   // (2048, 512)
    const float* ent = (const float*)d_in[1];   // (40000, 512)
    const float* cb  = (const float*)d_in[2];   // (2048, 512)
    float* out = (float*)d_out;                 // [score | vq_loss | idx]

    char* ws = (char*)d_ws;
    const bool pre = ws_size >= 100ull * 1024 * 1024;

    // region0: partial (20.48 MB) during dist/merge, then quantb (40.96 MB).
    // rescore (writer of quantb) runs after cand_merge (last reader of partial).
    float4*         partial = (float4*)(ws);
    unsigned short* quantb  = (unsigned short*)(ws);
    size_t off = 40960000;
    unsigned short* ehi = nullptr;
    if (pre) { ehi = (unsigned short*)(ws + off); off += 40960000; }
    unsigned short* chi = (unsigned short*)(ws + off); off += 2097152;
    unsigned short* qb  = (unsigned short*)(ws + off); off += 2097152;
    int*            cand= (int*)(ws + off);            off += 1280000;
    float*          c2  = (float*)(ws + off);          off += 8192;
    float*          acc = (float*)(ws + off);          off += 4;

    hipMemsetAsync(acc, 0, sizeof(float), stream);

    c2_kernel<<<NK / 4, 256, 0, stream>>>(cb, c2);
    cvt_bf16_kernel<<<NK * ND / 1024, 256, 0, stream>>>(cb, chi);
    cvt_bf16_kernel<<<Q * ND / 1024, 256, 0, stream>>>(qry, qb);
    if (pre) {
        cvt_bf16_kernel<<<NB * ND / 1024, 256, 0, stream>>>(ent, ehi);
        dist_mfma_kernel<true><<<1256, 512, 0, stream>>>(
            ent, ehi, chi, c2, partial);
    } else {
        dist_mfma_kernel<false><<<1256, 512, 0, stream>>>(
            ent, nullptr, chi, c2, partial);
    }
    cand_merge_kernel<<<(NB + 255) / 256, 256, 0, stream>>>(partial, cand);
    rescore_kernel<<<NB, 512, 0, stream>>>(ent, cb, c2, cand, quantb,
                                           out + SCORE_SIZE + 1, acc);
    vq_final_kernel<<<1, 1, 0, stream>>>(acc, out + SCORE_SIZE);
    score_kernel<<<1256, 512, 0, stream>>>(qb, quantb, out);
}

// Round 3
// 1920.373 us; speedup vs baseline: 1.0277x; 1.0086x over previous
//
#include <hip/hip_runtime.h>
#include <stdint.h>

#define Q    2048
#define NB   40000
#define NK   2048
#define ND   512
#define SCORE_SIZE (Q * NB)   // 81,920,000

#define BM 256
#define BN 256
#define BK 64

typedef __bf16 bf16;
typedef bf16  bf16x8 __attribute__((ext_vector_type(8)));
typedef float f32x4  __attribute__((ext_vector_type(4)));

__device__ __forceinline__ unsigned short f2bf_rne(float f) {
    unsigned int u = __float_as_uint(f);
    u += 0x7FFFu + ((u >> 16) & 1u);
    return (unsigned short)(u >> 16);
}

// async global->LDS 16B: LDS side is wave-uniform base + lane*16 (m97/m104)
__device__ __forceinline__ void gl2lds16(const void* g, void* l) {
    __builtin_amdgcn_global_load_lds(
        (const __attribute__((address_space(1))) void*)g,
        (__attribute__((address_space(3))) void*)l, 16, 0, 0);
}

// ---------------------------------------------------------------- c2 = ||cb_k||^2
__global__ __launch_bounds__(256) void c2_kernel(const float* __restrict__ cb,
                                                 float* __restrict__ c2) {
    int wave = threadIdx.x >> 6, lane = threadIdx.x & 63;
    int row  = blockIdx.x * 4 + wave;          // grid = NK/4 = 512
    const float4* p = (const float4*)(cb + (size_t)row * ND);
    float4 a = p[lane];
    float4 b = p[lane + 64];
    float s = a.x*a.x + a.y*a.y + a.z*a.z + a.w*a.w
            + b.x*b.x + b.y*b.y + b.z*b.z + b.w*b.w;
    #pragma unroll
    for (int off = 32; off; off >>= 1) s += __shfl_down(s, off);
    if (lane == 0) c2[row] = s;
}

// ---------------------------------------------------------- fp32 -> bf16 (RNE)
__global__ __launch_bounds__(256) void cvt_bf16_kernel(const float* __restrict__ src,
                                                       unsigned short* __restrict__ dst) {
    int i = (blockIdx.x * 256 + threadIdx.x) * 4;
    float4 v = *(const float4*)(src + i);
    uint2 u;
    u.x = (unsigned int)f2bf_rne(v.x) | ((unsigned int)f2bf_rne(v.y) << 16);
    u.y = (unsigned int)f2bf_rne(v.z) | ((unsigned int)f2bf_rne(v.w) << 16);
    *(uint2*)(dst + i) = u;
}

// top-2 insert with first-index tie-break
__device__ __forceinline__ void top2_insert(float& v1, int& i1, float& v2, int& i2,
                                            float w, int j) {
    if (w < v1 || (w == v1 && j < i1)) { v2 = v1; i2 = i1; v1 = w; i1 = j; }
    else if (w < v2 || (w == v2 && j < i2)) { v2 = w; i2 = j; }
}

// 256x256 tile MFMA step: 8 waves (2M x 4N), per-wave 128x64 output.
__device__ __forceinline__ void mfma_tile256(const unsigned short* __restrict__ Ab,
                                             const unsigned short* __restrict__ Bb,
                                             f32x4 (&acc)[8][4],
                                             int wm, int wn, int lr, int quad) {
    #pragma unroll
    for (int kq = 0; kq < 2; ++kq) {
        bf16x8 af[8], bfr[4];
        #pragma unroll
        for (int mi = 0; mi < 8; ++mi) {
            int r = wm * 128 + mi * 16 + lr;
            int ch = (kq * 4 + quad) ^ (lr & 7);
            af[mi] = *(const bf16x8*)(Ab + ((size_t)r * 8 + ch) * 8);
        }
        #pragma unroll
        for (int ni = 0; ni < 4; ++ni) {
            int r = wn * 64 + ni * 16 + lr;
            int ch = (kq * 4 + quad) ^ (lr & 7);
            bfr[ni] = *(const bf16x8*)(Bb + ((size_t)r * 8 + ch) * 8);
        }
        #pragma unroll
        for (int mi = 0; mi < 8; ++mi)
            #pragma unroll
            for (int ni = 0; ni < 4; ++ni)
                acc[mi][ni] = __builtin_amdgcn_mfma_f32_16x16x32_bf16(
                    af[mi], bfr[ni], acc[mi][ni], 0, 0, 0);
    }
}

// bijective chunked XCD swizzle: nwg = 1256 = 8 * 157.
__device__ __forceinline__ void tile_coords8(int bid, int& fast8, int& slow157) {
    int wg = (bid & 7) * 157 + (bid >> 3);
    fast8   = wg & 7;
    slow157 = wg >> 3;
}

// unified bf16 stage: P0 rows (a0+r, clamp lim0) -> B0, P1 rows (b0+r, clamp lim1) -> B1.
// 8 gl2lds (VMEM) per wave per call — the vmcnt bookkeeping unit.
__device__ __forceinline__ void stage2(
        const unsigned short* __restrict__ P0, int a0, int lim0,
        const unsigned short* __restrict__ P1, int b0, int lim1,
        unsigned short* B0, unsigned short* B1, int kt, int tid, int wave) {
    #pragma unroll
    for (int j = 0; j < 4; ++j) {
        int q = j * 512 + tid;            // chunk id within 256x64 tile
        int r = q >> 3;                   // 0..255
        int cs = (q & 7) ^ (r & 7);       // pre-swizzled global chunk
        int ra = a0 + r; ra = ra < lim0 ? ra : lim0 - 1;
        int rb = b0 + r; rb = rb < lim1 ? rb : lim1 - 1;
        gl2lds16(P0 + (size_t)ra * ND + kt + cs * 8,
                 B0 + (size_t)(j * 512 + wave * 64) * 8);   // wave-uniform base
        gl2lds16(P1 + (size_t)rb * ND + kt + cs * 8,
                 B1 + (size_t)(j * 512 + wave * 64) * 8);
    }
}

// fp32 fallback stage (non-PRE only; not used when workspace is large enough)
__device__ __forceinline__ void stage_dist_f32(
        const float* __restrict__ entf, const unsigned short* __restrict__ chi,
        unsigned short* Eb, unsigned short* Cb,
        int b0, int k0, int kt, int tid, int wave) {
    #pragma unroll
    for (int j = 0; j < 4; ++j) {
        int q = j * 512 + tid;
        int r = q >> 3;
        int cs = (q & 7) ^ (r & 7);
        gl2lds16(chi + (size_t)(k0 + r) * ND + kt + cs * 8,
                 Cb + (size_t)(j * 512 + wave * 64) * 8);
        int br = b0 + r; br = br < NB ? br : NB - 1;
        const float* s = entf + (size_t)br * ND + kt + cs * 8;
        float4 a = *(const float4*)s;
        float4 b = *(const float4*)(s + 4);
        uint4 hp;
        hp.x = (unsigned int)f2bf_rne(a.x) | ((unsigned int)f2bf_rne(a.y) << 16);
        hp.y = (unsigned int)f2bf_rne(a.z) | ((unsigned int)f2bf_rne(a.w) << 16);
        hp.z = (unsigned int)f2bf_rne(b.x) | ((unsigned int)f2bf_rne(b.y) << 16);
        hp.w = (unsigned int)f2bf_rne(b.z) | ((unsigned int)f2bf_rne(b.w) << 16);
        *(uint4*)(Eb + (size_t)q * 8) = hp;
    }
}

// counted-vmcnt 2-deep pipelined K-loop (T3/T4): loads never drain to 0 mid-loop.
// Contract: within the loop the ONLY VMEM ops are stage2's 8 gl2lds per wave.
#define PIPE_KLOOP(STAGE_T2, COMPUTE_T)                                        \
    _Pragma("unroll")                                                          \
    for (int t = 0; t < 8; ++t) {                                              \
        if (t < 7) asm volatile("s_waitcnt vmcnt(8)" ::: "memory");            \
        else       asm volatile("s_waitcnt vmcnt(0)" ::: "memory");            \
        __builtin_amdgcn_sched_barrier(0);                                     \
        __builtin_amdgcn_s_barrier();      /* tile t landed in all waves */    \
        __builtin_amdgcn_sched_barrier(0);                                     \
        COMPUTE_T;                                                             \
        asm volatile("s_waitcnt lgkmcnt(0)" ::: "memory");                     \
        __builtin_amdgcn_sched_barrier(0);                                     \
        __builtin_amdgcn_s_barrier();      /* all waves done reading buf */    \
        __builtin_amdgcn_sched_barrier(0);                                     \
        if (t < 6) { STAGE_T2; }           /* tile t+2 into freed buffer */    \
    }

// ---------------- approx distance GEMM: s(b,k) = c2[k] - 2*bf16dot(x_b, c_k)
template<bool PRE>
__global__ __launch_bounds__(512, 2) void dist_mfma_kernel(
        const float* __restrict__ entf, const unsigned short* __restrict__ ehi,
        const unsigned short* __restrict__ chi,
        const float* __restrict__ c2g, float4* __restrict__ partial) {
    __shared__ unsigned short Es[2][BM * BK];   // 2 x 32 KB
    __shared__ unsigned short Cs[2][BN * BK];   // 2 x 32 KB  (128 KB total)
    int tid = threadIdx.x;
    int by, bx;
    tile_coords8(blockIdx.x, by, bx);  // by: 8 k-tiles (fast), bx: 157 b-tiles
    int b0 = bx * BM;
    int k0 = by * BN;
    int lane = tid & 63, wave = tid >> 6;
    int wm = wave >> 2, wn = wave & 3;
    int lr = lane & 15, quad = lane >> 4;

    f32x4 acc[8][4] = {};

    if constexpr (PRE) {
        // prologue: issue tiles 0 and 1 (16 VMEM/wave in flight), no wait yet
        stage2(ehi, b0, NB, chi, k0, NK, Es[0], Cs[0], 0,  tid, wave);
        stage2(ehi, b0, NB, chi, k0, NK, Es[1], Cs[1], BK, tid, wave);
        PIPE_KLOOP(
            stage2(ehi, b0, NB, chi, k0, NK, Es[t & 1], Cs[t & 1],
                   (t + 2) * BK, tid, wave),
            mfma_tile256(Es[t & 1], Cs[t & 1], acc, wm, wn, lr, quad));
    } else {
        stage_dist_f32(entf, chi, Es[0], Cs[0], b0, k0, 0, tid, wave);
        __syncthreads();
        for (int t = 0; t < 8; ++t) {
            if (t < 7)
                stage_dist_f32(entf, chi, Es[(t + 1) & 1], Cs[(t + 1) & 1],
                               b0, k0, (t + 1) * BK, tid, wave);
            mfma_tile256(Es[t & 1], Cs[t & 1], acc, wm, wn, lr, quad);
            __syncthreads();
        }
    }

    float c2v[4];
    #pragma unroll
    for (int ni = 0; ni < 4; ++ni) c2v[ni] = c2g[k0 + wn * 64 + ni * 16 + lr];

    // top-2 per 64-code group; group id = by*4 + wn in [0,32)
    #pragma unroll
    for (int mi = 0; mi < 8; ++mi) {
        #pragma unroll
        for (int rr = 0; rr < 4; ++rr) {
            float v1 = 3.4e38f, v2 = 3.4e38f;
            int i1 = 0x7FFFFFFF, i2 = 0x7FFFFFFF;
            #pragma unroll
            for (int ni = 0; ni < 4; ++ni) {
                float w = c2v[ni] - 2.0f * acc[mi][ni][rr];
                top2_insert(v1, i1, v2, i2, w, k0 + wn * 64 + ni * 16 + lr);
            }
            #pragma unroll
            for (int off = 1; off < 16; off <<= 1) {
                float ov1 = __shfl_xor(v1, off); int oi1 = __shfl_xor(i1, off);
                float ov2 = __shfl_xor(v2, off); int oi2 = __shfl_xor(i2, off);
                top2_insert(v1, i1, v2, i2, ov1, oi1);
                top2_insert(v1, i1, v2, i2, ov2, oi2);
            }
            int b = b0 + wm * 128 + mi * 16 + quad * 4 + rr;
            if (lr == 0 && b < NB)
                partial[(size_t)(by * 4 + wn) * NB + b] =
                    make_float4(v1, __int_as_float(i1), v2, __int_as_float(i2));
        }
    }
}

// ------------------------------ merge 32 group top-2s -> global approx top-8
__global__ __launch_bounds__(256) void cand_merge_kernel(
        const float4* __restrict__ partial, int* __restrict__ cand) {
    int b = blockIdx.x * 256 + threadIdx.x;
    if (b >= NB) return;
    float tv[8]; int ti[8];
    #pragma unroll
    for (int s = 0; s < 8; ++s) { tv[s] = 3.4e38f; ti[s] = 0x7FFFFFFF; }
    for (int g = 0; g < 32; ++g) {
        float4 p = partial[(size_t)g * NB + b];
        float pv[2] = {p.x, p.z};
        int   pi[2] = {__float_as_int(p.y), __float_as_int(p.w)};
        #pragma unroll
        for (int t = 0; t < 2; ++t) {
            float w = pv[t]; int j = pi[t];
            #pragma unroll
            for (int s = 0; s < 8; ++s) {
                if (w < tv[s] || (w == tv[s] && j < ti[s])) {
                    float tmpv = tv[s]; int tmpi = ti[s];
                    tv[s] = w; ti[s] = j; w = tmpv; j = tmpi;
                }
            }
        }
    }
    #pragma unroll
    for (int s = 0; s < 8; ++s) cand[(size_t)b * 8 + s] = ti[s];
}

// ------- exact fp32 rescore of 8 candidates + fused quant gather + vq_loss
__global__ __launch_bounds__(512) void rescore_kernel(
        const float* __restrict__ ent, const float* __restrict__ cb,
        const float* __restrict__ c2g, const int* __restrict__ cand,
        unsigned short* __restrict__ quantb, float* __restrict__ out_idx,
        float* __restrict__ acc) {
    int b = blockIdx.x;                 // grid = NB, 8 waves = 8 candidates
    int wave = threadIdx.x >> 6, lane = threadIdx.x & 63;
    int k = cand[(size_t)b * 8 + wave];
    const float4* xp = (const float4*)(ent + (size_t)b * ND);
    const float4* cp = (const float4*)(cb + (size_t)k * ND);
    float4 x0 = xp[lane * 2], x1 = xp[lane * 2 + 1];
    float4 c0 = cp[lane * 2], c1 = cp[lane * 2 + 1];
    float s = x0.x*c0.x + x0.y*c0.y + x0.z*c0.z + x0.w*c0.w
            + x1.x*c1.x + x1.y*c1.y + x1.z*c1.z + x1.w*c1.w;
    #pragma unroll
    for (int off = 32; off; off >>= 1) s += __shfl_down(s, off);
    __shared__ float vws[8];
    __shared__ int   kws[8];
    __shared__ int   win;
    if (lane == 0) { vws[wave] = c2g[k] - 2.0f * s; kws[wave] = k; }
    __syncthreads();
    if (threadIdx.x == 0) {
        float bv = vws[0]; int bk = kws[0], bw = 0;
        #pragma unroll
        for (int w = 1; w < 8; ++w) {
            if (vws[w] < bv || (vws[w] == bv && kws[w] < bk)) {
                bv = vws[w]; bk = kws[w]; bw = w;
            }
        }
        win = bw;
        out_idx[b] = (float)bk;
    }
    __syncthreads();
    if (wave == win) {
        uint4 qp;
        qp.x = (unsigned int)f2bf_rne(c0.x) | ((unsigned int)f2bf_rne(c0.y) << 16);
        qp.y = (unsigned int)f2bf_rne(c0.z) | ((unsigned int)f2bf_rne(c0.w) << 16);
        qp.z = (unsigned int)f2bf_rne(c1.x) | ((unsigned int)f2bf_rne(c1.y) << 16);
        qp.w = (unsigned int)f2bf_rne(c1.z) | ((unsigned int)f2bf_rne(c1.w) << 16);
        *(uint4*)(quantb + (size_t)b * ND + lane * 8) = qp;
        float d0 = c0.x - x0.x, d1 = c0.y - x0.y, d2 = c0.z - x0.z, d3 = c0.w - x0.w;
        float d4 = c1.x - x1.x, d5 = c1.y - x1.y, d6 = c1.z - x1.z, d7 = c1.w - x1.w;
        float l = d0*d0 + d1*d1 + d2*d2 + d3*d3 + d4*d4 + d5*d5 + d6*d6 + d7*d7;
        #pragma unroll
        for (int off = 32; off; off >>= 1) l += __shfl_down(l, off);
        if (lane == 0) atomicAdd(acc, l);
    }
}

__global__ void vq_final_kernel(const float* __restrict__ acc, float* __restrict__ out) {
    out[0] = 1.25f * acc[0] / (float)(NB * ND);
}

// ---------- score = query @ quant^T, same counted-vmcnt pipelined structure
__global__ __launch_bounds__(512, 2) void score_kernel(
        const unsigned short* __restrict__ Aq, const unsigned short* __restrict__ Bq,
        float* __restrict__ C) {
    __shared__ unsigned short As[2][BM * BK];
    __shared__ unsigned short Bs[2][BN * BK];
    int tid = threadIdx.x;
    int bm, bn;
    tile_coords8(blockIdx.x, bm, bn);  // bm: 8 Q-tiles (fast), bn: 157 B-tiles
    int m0 = bm * BM;
    int n0 = bn * BN;
    int lane = tid & 63, wave = tid >> 6;
    int wm = wave >> 2, wn = wave & 3;
    int lr = lane & 15, quad = lane >> 4;

    f32x4 acc[8][4] = {};

    stage2(Aq, m0, Q, Bq, n0, NB, As[0], Bs[0], 0,  tid, wave);
    stage2(Aq, m0, Q, Bq, n0, NB, As[1], Bs[1], BK, tid, wave);
    PIPE_KLOOP(
        stage2(Aq, m0, Q, Bq, n0, NB, As[t & 1], Bs[t & 1],
               (t + 2) * BK, tid, wave),
        mfma_tile256(As[t & 1], Bs[t & 1], acc, wm, wn, lr, quad));

    // C/D layout (verified m89/m91): col = lane&15, row = (lane>>4)*4 + reg
    #pragma unroll
    for (int mi = 0; mi < 8; ++mi) {
        #pragma unroll
        for (int ni = 0; ni < 4; ++ni) {
            int col = n0 + wn * 64 + ni * 16 + lr;
            if (col < NB) {
                #pragma unroll
                for (int r = 0; r < 4; ++r) {
                    int row = m0 + wm * 128 + mi * 16 + quad * 4 + r;
                    C[(size_t)row * NB + col] = acc[mi][ni][r];
                }
            }
        }
    }
}

extern "C" void kernel_launch(void* const* d_in, const int* in_sizes, int n_in,
                              void* d_out, int out_size, void* d_ws, size_t ws_size,
                              hipStream_t stream) {
    const float* qry = (const float*)d_in[0];   // (2048, 512)
    const float* ent = (const float*)d_in[1];   // (40000, 512)
    const float* cb  = (const float*)d_in[2];   // (2048, 512)
    float* out = (float*)d_out;                 // [score | vq_loss | idx]

    char* ws = (char*)d_ws;
    const bool pre = ws_size >= 100ull * 1024 * 1024;

    // region0: partial (20.48 MB) during dist/merge, then quantb (40.96 MB).
    // rescore (writer of quantb) runs after cand_merge (last reader of partial).
    float4*         partial = (float4*)(ws);
    unsigned short* quantb  = (unsigned short*)(ws);
    size_t off = 40960000;
    unsigned short* ehi = nullptr;
    if (pre) { ehi = (unsigned short*)(ws + off); off += 40960000; }
    unsigned short* chi = (unsigned short*)(ws + off); off += 2097152;
    unsigned short* qb  = (unsigned short*)(ws + off); off += 2097152;
    int*            cand= (int*)(ws + off);            off += 1280000;
    float*          c2  = (float*)(ws + off);          off += 8192;
    float*          acc = (float*)(ws + off);          off += 4;

    hipMemsetAsync(acc, 0, sizeof(float), stream);

    c2_kernel<<<NK / 4, 256, 0, stream>>>(cb, c2);
    cvt_bf16_kernel<<<NK * ND / 1024, 256, 0, stream>>>(cb, chi);
    cvt_bf16_kernel<<<Q * ND / 1024, 256, 0, stream>>>(qry, qb);
    if (pre) {
        cvt_bf16_kernel<<<NB * ND / 1024, 256, 0, stream>>>(ent, ehi);
        dist_mfma_kernel<true><<<1256, 512, 0, stream>>>(
            ent, ehi, chi, c2, partial);
    } else {
        dist_mfma_kernel<false><<<1256, 512, 0, stream>>>(
            ent, nullptr, chi, c2, partial);
    }
    cand_merge_kernel<<<(NB + 255) / 256, 256, 0, stream>>>(partial, cand);
    rescore_kernel<<<NB, 512, 0, stream>>>(ent, cb, c2, cand, quantb,
                                           out + SCORE_SIZE + 1, acc);
    vq_final_kernel<<<1, 1, 0, stream>>>(acc, out + SCORE_SIZE);
    score_kernel<<<1256, 512, 0, stream>>>(qb, quantb, out);
}